// Round 5
// baseline (154.477 us; speedup 1.0000x reference)
//
#include <hip/hip_runtime.h>
#include <math.h>

#define RES_W 256
#define RES_H 256
#define MAX_SAMPLES 384
#define TF_RES 128
#define NSEG 4
#define SEG_LEN 96   // 384 / NSEG

__global__ __launch_bounds__(256, 4) void raycast_kernel(
    const float* __restrict__ vol,    // [256,256,256] x-major: idx = (x<<16)+(y<<8)+z
    const float* __restrict__ tf,     // [128,4]
    const float* __restrict__ cam_p,  // [3]
    const int*   __restrict__ sr_p,   // [1]
    float* __restrict__ out)          // [256,256,5]  idx = (w*256+h)*5+c
{
    #pragma clang fp contract(off)

    __shared__ float4 tf_s[TF_RES];
    // per-segment partial composites, combined in order at the end
    __shared__ float seg_r[NSEG][64], seg_g[NSEG][64], seg_b[NSEG][64];
    __shared__ float seg_a[NSEG][64], seg_T[NSEG][64], seg_d[NSEG][64];
    __shared__ int   seg_f[NSEG][64];

    const int tid  = (int)threadIdx.x;   // 0..255
    const int lane = tid & 63;
    const int seg  = tid >> 6;           // 0..3 — this wave's sample segment

    if (tid < TF_RES) tf_s[tid] = ((const float4*)tf)[tid];

    // XCD-aware tile swizzle: block b -> XCD b%8 gets a contiguous image slab.
    const int b    = (int)blockIdx.x;          // 0..1023
    const int tile = (b % 8) * 128 + (b / 8);  // 0..1023
    const int tile_h = tile % 32;
    const int tile_w = tile / 32;
    const int h = tile_h * 8 + (lane % 8);     // H index (v axis)
    const int w = tile_w * 8 + (lane / 8);     // W index (u axis)

    const float cx = cam_p[0], cy = cam_p[1], cz = cam_p[2];
    const int   sr_i = sr_p[0];
    const float srf = (float)sr_i;

    // ---- camera basis, fp32, numpy op order, no FMA ----
    float nx = -cx, ny = -cy, nz = -cz;
    float fl = __fsqrt_rn((nx*nx + ny*ny) + nz*nz);
    float fx = nx / fl, fy = ny / fl, fz = nz / fl;
    float rxu = 0.0f - fz;
    float rzu = fx;
    float rl = __fsqrt_rn((rxu*rxu + 0.0f) + rzu*rzu);
    float rx = rxu / rl, rz = rzu / rl;
    float ux = 0.0f - rz*fy;
    float uy = rz*fx - rx*fz;
    float uz = rx*fy;

    const float ang32 = (float)((30.0 * 0.017453292519943295) * 0.5);
    const float tan_half = (float)tan((double)ang32);

    float uu = ((((float)w + 0.5f) / 256.0f) * 2.0f - 1.0f) * tan_half;
    float vv = ((((float)h + 0.5f) / 256.0f) * 2.0f - 1.0f) * tan_half;

    float dx = (fx + uu*rx) + vv*ux;
    float dy = (fy + 0.0f ) + vv*uy;
    float dz = (fz + uu*rz) + vv*uz;
    float dl = __fsqrt_rn((dx*dx + dy*dy) + dz*dz);
    dx = dx / dl; dy = dy / dl; dz = dz / dl;

    float ivx = 1.0f/dx, ivy = 1.0f/dy, ivz = 1.0f/dz;
    float tlx = (-1.0f - cx)*ivx, thx = (1.0f - cx)*ivx;
    float tly = (-1.0f - cy)*ivy, thy = (1.0f - cy)*ivy;
    float tlz = (-1.0f - cz)*ivz, thz = (1.0f - cz)*ivz;
    float tmin = fmaxf(fmaxf(fminf(tlx,thx), fminf(tly,thy)), fminf(tlz,thz));
    float tmax = fminf(fminf(fmaxf(tlx,thx), fmaxf(tly,thy)), fmaxf(tlz,thz));
    bool hit = (tmax >= 0.0f) && (tmin <= tmax);

    float entry = fmaxf(tmin, 0.1f);
    float dist  = hit ? fmaxf(tmax - entry, 0.0f) : 0.0f;
    float nsf   = fminf(fmaxf(ceilf(((dist * 0.5f) * 256.0f) * srf), 1.0f), 384.0f);
    int   ns    = (int)nsf;
    float step  = dist / nsf;

    __syncthreads();   // TF staged

    float rgb_r = 0.0f, rgb_g = 0.0f, rgb_b = 0.0f;
    float acc = 0.0f;
    float Texcl = 1.0f;       // LOCAL transmittance of this segment
    float depth = 1.0f;
    bool  found = false;

    const int k_begin = seg * SEG_LEN;
    const int k_end   = min(ns, (seg + 1) * SEG_LEN);

    if (hit && k_begin < k_end) {
        for (int k0 = k_begin; k0 < k_end; k0 += 2) {
            // ---- phase A: positions + 16 independent gathers ----
            float t_[2], val[2][8], ffx_[2], ffy_[2], ffz_[2];
            #pragma unroll
            for (int j = 0; j < 2; ++j) {
                float t  = entry + ((float)(k0 + j) + 0.5f) * step;
                t_[j] = t;
                float px = (cx + t*dx);
                float py = (cy + t*dy);
                float pz = (cz + t*dz);
                px = ((px * 0.5f) + 0.5f) * 255.0f;
                py = ((py * 0.5f) + 0.5f) * 255.0f;
                pz = ((pz * 0.5f) + 0.5f) * 255.0f;
                px = fminf(fmaxf(px, 0.0f), 255.0f);
                py = fminf(fmaxf(py, 0.0f), 255.0f);
                pz = fminf(fmaxf(pz, 0.0f), 255.0f);
                int x0 = (int)floorf(px), y0 = (int)floorf(py), z0 = (int)floorf(pz);
                ffx_[j] = px - (float)x0;
                ffy_[j] = py - (float)y0;
                ffz_[j] = pz - (float)z0;
                int x1 = min(x0 + 1, 255);
                int y1 = min(y0 + 1, 255);
                int z1 = min(z0 + 1, 255);
                int bx0 = x0 << 16, bx1 = x1 << 16;
                int by0 = y0 << 8,  by1 = y1 << 8;
                val[j][0] = vol[bx0 + by0 + z0];
                val[j][1] = vol[bx1 + by0 + z0];
                val[j][2] = vol[bx0 + by1 + z0];
                val[j][3] = vol[bx1 + by1 + z0];
                val[j][4] = vol[bx0 + by0 + z1];
                val[j][5] = vol[bx1 + by0 + z1];
                val[j][6] = vol[bx0 + by1 + z1];
                val[j][7] = vol[bx1 + by1 + z1];
            }
            // ---- phase B: intensities + TF LDS reads ----
            float tfr_[2];
            float4 ca_[2], cb_[2];
            #pragma unroll
            for (int j = 0; j < 2; ++j) {
                float omx = 1.0f - ffx_[j], omy = 1.0f - ffy_[j], omz = 1.0f - ffz_[j];
                float c00 = val[j][0]*omx + val[j][1]*ffx_[j];
                float c10 = val[j][2]*omx + val[j][3]*ffx_[j];
                float c01 = val[j][4]*omx + val[j][5]*ffx_[j];
                float c11 = val[j][6]*omx + val[j][7]*ffx_[j];
                float c0  = c00*omy + c10*ffy_[j];
                float c1  = c01*omy + c11*ffy_[j];
                float intensity = c0*omz + c1*ffz_[j];
                float xi = fminf(fmaxf(intensity, 0.0f), 1.0f) * 127.0f;
                int lo  = (int)floorf(xi);
                int hi2 = min(lo + 1, 127);
                tfr_[j] = xi - (float)lo;
                ca_[j] = tf_s[lo];
                cb_[j] = tf_s[hi2];
            }
            // ---- phase C: ordered compositing (reference op order) ----
            #pragma unroll
            for (int j = 0; j < 2; ++j) {
                if (k0 + j < k_end) {
                    float tfr = tfr_[j];
                    float omt = 1.0f - tfr;
                    float cr  = ca_[j].x*omt + cb_[j].x*tfr;
                    float cg  = ca_[j].y*omt + cb_[j].y*tfr;
                    float cbb = ca_[j].z*omt + cb_[j].z*tfr;
                    float a   = ca_[j].w*omt + cb_[j].w*tfr;
                    if (sr_i == 1) {
                        a = 1.0f - (1.0f - a);
                    } else {
                        a = 1.0f - powf(1.0f - a, 1.0f / srf);
                    }
                    float one_m = 1.0f - a;
                    float wgt = Texcl * a;
                    rgb_r += wgt * cr;
                    rgb_g += wgt * cg;
                    rgb_b += wgt * cbb;
                    acc   += wgt;
                    if (!found && a > 1e-3f) {
                        found = true;
                        depth = (t_[j] - 0.1f) / 99.9f;
                    }
                    Texcl = Texcl * one_m;
                }
            }
            // local early-exit: dropped tail contributes <= T_prefix*Texcl <= 1e-7
            if (found && Texcl < 1e-7f) break;
        }
    }

    seg_r[seg][lane] = rgb_r;
    seg_g[seg][lane] = rgb_g;
    seg_b[seg][lane] = rgb_b;
    seg_a[seg][lane] = acc;
    seg_T[seg][lane] = Texcl;
    seg_d[seg][lane] = depth;
    seg_f[seg][lane] = found ? 1 : 0;
    __syncthreads();

    // ---- ordered combine of the 4 segment records (wave 0) ----
    if (tid < 64) {
        float T = 1.0f, r = 0.0f, g = 0.0f, bb = 0.0f, ac = 0.0f, dp = 1.0f;
        bool fnd = false;
        #pragma unroll
        for (int s = 0; s < NSEG; ++s) {
            r  += T * seg_r[s][tid];
            g  += T * seg_g[s][tid];
            bb += T * seg_b[s][tid];
            ac += T * seg_a[s][tid];
            if (!fnd && seg_f[s][tid]) { fnd = true; dp = seg_d[s][tid]; }
            T = T * seg_T[s][tid];
        }
        int oi = (w * RES_H + h) * 5;   // tid<64 => lane==tid, w/h valid
        out[oi + 0] = r;
        out[oi + 1] = g;
        out[oi + 2] = bb;
        out[oi + 3] = ac;
        out[oi + 4] = dp;
    }
}

extern "C" void kernel_launch(void* const* d_in, const int* in_sizes, int n_in,
                              void* d_out, int out_size, void* d_ws, size_t ws_size,
                              hipStream_t stream) {
    const float* vol = (const float*)d_in[0];
    const float* tf  = (const float*)d_in[1];
    const float* cam = (const float*)d_in[2];
    const int*   sr  = (const int*)d_in[3];
    float* out = (float*)d_out;

    raycast_kernel<<<dim3(1024), dim3(256), 0, stream>>>(vol, tf, cam, sr, out);
}

// Round 6
// 116.543 us; speedup vs baseline: 1.3255x; 1.3255x over previous
//
#include <hip/hip_runtime.h>
#include <math.h>

#define RES_W 256
#define RES_H 256
#define TF_RES 128

// One wave = 2 rays; lanes 0-31 march samples of ray A, lanes 32-63 ray B.
// Compositing via 32-wide product-scan + butterfly reductions.
__global__ __launch_bounds__(256, 8) void raycast_kernel(
    const float* __restrict__ vol,    // [256,256,256] x-major: idx = (x<<16)+(y<<8)+z
    const float* __restrict__ tf,     // [128,4]
    const float* __restrict__ cam_p,  // [3]
    const int*   __restrict__ sr_p,   // [1]
    float* __restrict__ out)          // [256,256,5]  idx = (w*256+h)*5+c
{
    #pragma clang fp contract(off)

    __shared__ float tfR[TF_RES], tfG[TF_RES], tfB[TF_RES], tfA[TF_RES];
    const int tid = (int)threadIdx.x;   // 0..255
    if (tid < TF_RES) {
        float4 e = ((const float4*)tf)[tid];
        tfR[tid] = e.x; tfG[tid] = e.y; tfB[tid] = e.z; tfA[tid] = e.w;
    }
    __syncthreads();

    const int lane = tid & 63;
    const int sub  = lane & 31;         // position within this ray's 32-lane half

    // 8192 blocks x 8 rays. XCD swizzle: block b -> XCD b%8 gets contiguous slab.
    const int b  = (int)blockIdx.x;
    const int sb = (b & 7) * 1024 + (b >> 3);
    const int ray = sb * 8 + (tid >> 5);      // 0..65535, h-major
    const int h = ray & 255;                  // H index (v axis)
    const int w = ray >> 8;                   // W index (u axis)

    const float cx = cam_p[0], cy = cam_p[1], cz = cam_p[2];
    const int   sr_i = sr_p[0];
    const float srf = (float)sr_i;

    // ---- camera basis, fp32, numpy op order, no FMA (bit-matches reference) ----
    float nx = -cx, ny = -cy, nz = -cz;
    float fl = __fsqrt_rn((nx*nx + ny*ny) + nz*nz);
    float fx = nx / fl, fy = ny / fl, fz = nz / fl;
    float rxu = 0.0f - fz;
    float rzu = fx;
    float rl = __fsqrt_rn((rxu*rxu + 0.0f) + rzu*rzu);
    float rx = rxu / rl, rz = rzu / rl;
    float ux = 0.0f - rz*fy;
    float uy = rz*fx - rx*fz;
    float uz = rx*fy;

    const float ang32 = (float)((30.0 * 0.017453292519943295) * 0.5);
    const float tan_half = (float)tan((double)ang32);

    float uu = ((((float)w + 0.5f) / 256.0f) * 2.0f - 1.0f) * tan_half;
    float vv = ((((float)h + 0.5f) / 256.0f) * 2.0f - 1.0f) * tan_half;

    float dx = (fx + uu*rx) + vv*ux;
    float dy = (fy + 0.0f ) + vv*uy;
    float dz = (fz + uu*rz) + vv*uz;
    float dl = __fsqrt_rn((dx*dx + dy*dy) + dz*dz);
    dx = dx / dl; dy = dy / dl; dz = dz / dl;

    float ivx = 1.0f/dx, ivy = 1.0f/dy, ivz = 1.0f/dz;
    float tlx = (-1.0f - cx)*ivx, thx = (1.0f - cx)*ivx;
    float tly = (-1.0f - cy)*ivy, thy = (1.0f - cy)*ivy;
    float tlz = (-1.0f - cz)*ivz, thz = (1.0f - cz)*ivz;
    float tmin = fmaxf(fmaxf(fminf(tlx,thx), fminf(tly,thy)), fminf(tlz,thz));
    float tmax = fminf(fminf(fmaxf(tlx,thx), fmaxf(tly,thy)), fmaxf(tlz,thz));
    bool hit = (tmax >= 0.0f) && (tmin <= tmax);

    float entry = fmaxf(tmin, 0.1f);
    float dist  = hit ? fmaxf(tmax - entry, 0.0f) : 0.0f;
    float nsf   = fminf(fmaxf(ceilf(((dist * 0.5f) * 256.0f) * srf), 1.0f), 384.0f);
    int   ns    = (int)nsf;
    float step  = dist / nsf;

    float rgb_r = 0.0f, rgb_g = 0.0f, rgb_b = 0.0f, acc = 0.0f;
    float T_prev = 1.0f;      // transmittance entering current chunk (per ray)
    float depth = 1.0f;
    bool  found = false;

    for (int base = 0; ; ) {
        const int  k     = base + sub;
        const bool valid = hit && (k < ns);

        // ---- per-lane sample: position + 8 gathers + trilinear (reference op order) ----
        float t  = entry + ((float)k + 0.5f) * step;
        float px = (cx + t*dx);
        float py = (cy + t*dy);
        float pz = (cz + t*dz);
        px = ((px * 0.5f) + 0.5f) * 255.0f;
        py = ((py * 0.5f) + 0.5f) * 255.0f;
        pz = ((pz * 0.5f) + 0.5f) * 255.0f;
        px = fminf(fmaxf(px, 0.0f), 255.0f);
        py = fminf(fmaxf(py, 0.0f), 255.0f);
        pz = fminf(fmaxf(pz, 0.0f), 255.0f);
        int x0 = (int)floorf(px), y0 = (int)floorf(py), z0 = (int)floorf(pz);
        float ffx = px - (float)x0;
        float ffy = py - (float)y0;
        float ffz = pz - (float)z0;
        int x1 = min(x0 + 1, 255);
        int y1 = min(y0 + 1, 255);
        int z1 = min(z0 + 1, 255);
        int bx0 = x0 << 16, bx1 = x1 << 16;
        int by0 = y0 << 8,  by1 = y1 << 8;
        float c000 = vol[bx0 + by0 + z0];
        float c100 = vol[bx1 + by0 + z0];
        float c010 = vol[bx0 + by1 + z0];
        float c110 = vol[bx1 + by1 + z0];
        float c001 = vol[bx0 + by0 + z1];
        float c101 = vol[bx1 + by0 + z1];
        float c011 = vol[bx0 + by1 + z1];
        float c111 = vol[bx1 + by1 + z1];

        float omx = 1.0f - ffx, omy = 1.0f - ffy, omz = 1.0f - ffz;
        float c00 = c000*omx + c100*ffx;
        float c10 = c010*omx + c110*ffx;
        float c01 = c001*omx + c101*ffx;
        float c11 = c011*omx + c111*ffx;
        float c0  = c00*omy + c10*ffy;
        float c1  = c01*omy + c11*ffy;
        float intensity = c0*omz + c1*ffz;

        // ---- TF lookup (SoA LDS: b32 reads, <=2-way bank aliasing = free) ----
        float xi = fminf(fmaxf(intensity, 0.0f), 1.0f) * 127.0f;
        int lo  = (int)floorf(xi);
        int hi2 = min(lo + 1, 127);
        float tfr = xi - (float)lo;
        float omt = 1.0f - tfr;
        float cr  = tfR[lo]*omt + tfR[hi2]*tfr;
        float cg  = tfG[lo]*omt + tfG[hi2]*tfr;
        float cbb = tfB[lo]*omt + tfB[hi2]*tfr;
        float a   = tfA[lo]*omt + tfA[hi2]*tfr;

        if (sr_i == 1) {
            a = 1.0f - (1.0f - a);               // double rounding, as numpy
        } else {
            a = 1.0f - powf(1.0f - a, 1.0f / srf);
        }
        if (!valid) a = 0.0f;                    // reference: a = where(valid, a, 0)
        float one_m = 1.0f - a;

        // ---- 32-wide inclusive product scan of one_m (Hillis-Steele) ----
        float x = one_m;
        #pragma unroll
        for (int off = 1; off < 32; off <<= 1) {
            float y = __shfl_up(x, off);
            if (sub >= off) x *= y;
        }
        float ex = __shfl_up(x, 1);
        if (sub == 0) ex = 1.0f;                 // exclusive transmittance within chunk

        float wgt = (T_prev * ex) * a;
        float pr = wgt * cr, pg = wgt * cg, pb = wgt * cbb, pa = wgt;
        // butterfly sum within the 32-lane half (xor masks 1..16 never cross bit5)
        #pragma unroll
        for (int m = 16; m >= 1; m >>= 1) {
            pr += __shfl_xor(pr, m);
            pg += __shfl_xor(pg, m);
            pb += __shfl_xor(pb, m);
            pa += __shfl_xor(pa, m);
        }
        rgb_r += pr; rgb_g += pg; rgb_b += pb; acc += pa;

        // ---- first-hit: min sample index with a > eps ----
        int hk = (valid && (a > 1e-3f)) ? k : 0x7FFFFFFF;
        #pragma unroll
        for (int m = 16; m >= 1; m >>= 1) hk = min(hk, __shfl_xor(hk, m));
        if (!found && hk != 0x7FFFFFFF) {
            found = true;
            float tfh = entry + ((float)hk + 0.5f) * step;   // same expr as reference
            depth = (tfh - 0.1f) / 99.9f;
        }

        // ---- chunk carry ----
        float Tc = __shfl(x, (lane & 32) | 31);  // inclusive product at end of half
        T_prev = T_prev * Tc;

        base += 32;
        // T<1e-7 implies found (else T >= (1-1e-3)^32 ~ 0.97); truncation err <= 1e-7
        bool active = hit && (base < ns) && (T_prev >= 1e-7f);
        if (__ballot(active) == 0ULL) break;
    }

    if (sub == 0) {
        int oi = (w * RES_H + h) * 5;
        out[oi + 0] = rgb_r;
        out[oi + 1] = rgb_g;
        out[oi + 2] = rgb_b;
        out[oi + 3] = acc;
        out[oi + 4] = depth;
    }
}

extern "C" void kernel_launch(void* const* d_in, const int* in_sizes, int n_in,
                              void* d_out, int out_size, void* d_ws, size_t ws_size,
                              hipStream_t stream) {
    const float* vol = (const float*)d_in[0];
    const float* tf  = (const float*)d_in[1];
    const float* cam = (const float*)d_in[2];
    const int*   sr  = (const int*)d_in[3];
    float* out = (float*)d_out;

    // 65536 rays, 2 rays/wave, 4 waves/block -> 8192 blocks
    raycast_kernel<<<dim3(8192), dim3(256), 0, stream>>>(vol, tf, cam, sr, out);
}

// Round 7
// 113.672 us; speedup vs baseline: 1.3590x; 1.0253x over previous
//
#include <hip/hip_runtime.h>
#include <math.h>

#define RES_W 256
#define RES_H 256
#define TF_RES 128

typedef float float2u __attribute__((ext_vector_type(2), aligned(4)));

// One wave = 2 rays; lanes 0-31 march samples of ray A, lanes 32-63 ray B.
// Transmittance via 32-wide product-scan; rgb/acc/first-hit reduced once at end.
__global__ __launch_bounds__(256, 8) void raycast_kernel(
    const float* __restrict__ vol,    // [256,256,256] x-major: idx = (x<<16)+(y<<8)+z
    const float* __restrict__ tf,     // [128,4]
    const float* __restrict__ cam_p,  // [3]
    const int*   __restrict__ sr_p,   // [1]
    float* __restrict__ out)          // [256,256,5]  idx = (w*256+h)*5+c
{
    #pragma clang fp contract(off)

    // 129-entry SoA tables: [128] duplicates [127] so (lo, lo+1) is always a
    // valid adjacent-dword pair -> ds_read2_b32, exact for the lo==127 edge.
    __shared__ float tfR[TF_RES + 1], tfG[TF_RES + 1], tfB[TF_RES + 1], tfA[TF_RES + 1];
    const int tid = (int)threadIdx.x;   // 0..255
    if (tid < TF_RES) {
        float4 e = ((const float4*)tf)[tid];
        tfR[tid] = e.x; tfG[tid] = e.y; tfB[tid] = e.z; tfA[tid] = e.w;
        if (tid == TF_RES - 1) {
            tfR[TF_RES] = e.x; tfG[TF_RES] = e.y; tfB[TF_RES] = e.z; tfA[TF_RES] = e.w;
        }
    }
    __syncthreads();

    const int lane = tid & 63;
    const int sub  = lane & 31;         // position within this ray's 32-lane half

    // 8192 blocks x 8 rays. XCD swizzle: block b -> XCD b%8 gets contiguous slab.
    const int b  = (int)blockIdx.x;
    const int sb = (b & 7) * 1024 + (b >> 3);
    const int ray = sb * 8 + (tid >> 5);      // 0..65535, h-major
    const int h = ray & 255;                  // H index (v axis)
    const int w = ray >> 8;                   // W index (u axis)

    const float cx = cam_p[0], cy = cam_p[1], cz = cam_p[2];
    const int   sr_i = sr_p[0];
    const float srf = (float)sr_i;

    // ---- camera basis, fp32, numpy op order, no FMA (bit-matches reference) ----
    float nx = -cx, ny = -cy, nz = -cz;
    float fl = __fsqrt_rn((nx*nx + ny*ny) + nz*nz);
    float fx = nx / fl, fy = ny / fl, fz = nz / fl;
    float rxu = 0.0f - fz;
    float rzu = fx;
    float rl = __fsqrt_rn((rxu*rxu + 0.0f) + rzu*rzu);
    float rx = rxu / rl, rz = rzu / rl;
    float ux = 0.0f - rz*fy;
    float uy = rz*fx - rx*fz;
    float uz = rx*fy;

    const float ang32 = (float)((30.0 * 0.017453292519943295) * 0.5);
    const float tan_half = (float)tan((double)ang32);

    float uu = ((((float)w + 0.5f) / 256.0f) * 2.0f - 1.0f) * tan_half;
    float vv = ((((float)h + 0.5f) / 256.0f) * 2.0f - 1.0f) * tan_half;

    float dx = (fx + uu*rx) + vv*ux;
    float dy = (fy + 0.0f ) + vv*uy;
    float dz = (fz + uu*rz) + vv*uz;
    float dl = __fsqrt_rn((dx*dx + dy*dy) + dz*dz);
    dx = dx / dl; dy = dy / dl; dz = dz / dl;

    float ivx = 1.0f/dx, ivy = 1.0f/dy, ivz = 1.0f/dz;
    float tlx = (-1.0f - cx)*ivx, thx = (1.0f - cx)*ivx;
    float tly = (-1.0f - cy)*ivy, thy = (1.0f - cy)*ivy;
    float tlz = (-1.0f - cz)*ivz, thz = (1.0f - cz)*ivz;
    float tmin = fmaxf(fmaxf(fminf(tlx,thx), fminf(tly,thy)), fminf(tlz,thz));
    float tmax = fminf(fminf(fmaxf(tlx,thx), fmaxf(tly,thy)), fmaxf(tlz,thz));
    bool hit = (tmax >= 0.0f) && (tmin <= tmax);

    float entry = fmaxf(tmin, 0.1f);
    float dist  = hit ? fmaxf(tmax - entry, 0.0f) : 0.0f;
    float nsf   = fminf(fmaxf(ceilf(((dist * 0.5f) * 256.0f) * srf), 1.0f), 384.0f);
    int   ns    = (int)nsf;
    float step  = dist / nsf;

    float rgb_r = 0.0f, rgb_g = 0.0f, rgb_b = 0.0f, acc = 0.0f;  // per-lane partials
    float T_prev = 1.0f;          // transmittance entering current chunk (per ray)
    int   hk_min = 0x7FFFFFFF;    // per-lane first-hit sample index

    for (int base = 0; ; ) {
        const int  k     = base + sub;
        const bool valid = hit && (k < ns);

        // ---- per-lane sample: position + 4 float2 z-pair gathers ----
        float t  = entry + ((float)k + 0.5f) * step;
        float px = (cx + t*dx);
        float py = (cy + t*dy);
        float pz = (cz + t*dz);
        px = ((px * 0.5f) + 0.5f) * 255.0f;
        py = ((py * 0.5f) + 0.5f) * 255.0f;
        pz = ((pz * 0.5f) + 0.5f) * 255.0f;
        px = fminf(fmaxf(px, 0.0f), 255.0f);
        py = fminf(fmaxf(py, 0.0f), 255.0f);
        pz = fminf(fmaxf(pz, 0.0f), 255.0f);
        int x0 = (int)floorf(px), y0 = (int)floorf(py), z0 = (int)floorf(pz);
        float ffx = px - (float)x0;
        float ffy = py - (float)y0;
        float ffz = pz - (float)z0;
        int x1 = min(x0 + 1, 255);
        int y1 = min(y0 + 1, 255);
        int zb = min(z0, 254);               // pair base; z0==255 -> ffz==0 exactly
        int bx0 = x0 << 16, bx1 = x1 << 16;
        int by0 = y0 << 8,  by1 = y1 << 8;
        float2u p00 = *(const float2u*)(vol + (bx0 + by0 + zb));
        float2u p10 = *(const float2u*)(vol + (bx1 + by0 + zb));
        float2u p01 = *(const float2u*)(vol + (bx0 + by1 + zb));
        float2u p11 = *(const float2u*)(vol + (bx1 + by1 + zb));
        bool ztop = (z0 == 255);
        float c000 = ztop ? p00.y : p00.x;   float c001 = p00.y;
        float c100 = ztop ? p10.y : p10.x;   float c101 = p10.y;
        float c010 = ztop ? p01.y : p01.x;   float c011 = p01.y;
        float c110 = ztop ? p11.y : p11.x;   float c111 = p11.y;

        float omx = 1.0f - ffx, omy = 1.0f - ffy, omz = 1.0f - ffz;
        float c00 = c000*omx + c100*ffx;
        float c10 = c010*omx + c110*ffx;
        float c01 = c001*omx + c101*ffx;
        float c11 = c011*omx + c111*ffx;
        float c0  = c00*omy + c10*ffy;
        float c1  = c01*omy + c11*ffy;
        float intensity = c0*omz + c1*ffz;

        // ---- TF lookup: adjacent-pair LDS reads (ds_read2_b32) ----
        float xi = fminf(fmaxf(intensity, 0.0f), 1.0f) * 127.0f;
        int lo  = (int)floorf(xi);
        float tfr = xi - (float)lo;
        float omt = 1.0f - tfr;
        float r0 = tfR[lo], r1 = tfR[lo + 1];
        float g0 = tfG[lo], g1 = tfG[lo + 1];
        float b0 = tfB[lo], b1 = tfB[lo + 1];
        float a0 = tfA[lo], a1 = tfA[lo + 1];
        float cr  = r0*omt + r1*tfr;
        float cg  = g0*omt + g1*tfr;
        float cbb = b0*omt + b1*tfr;
        float a   = a0*omt + a1*tfr;

        if (sr_i == 1) {
            a = 1.0f - (1.0f - a);               // double rounding, as numpy
        } else {
            a = 1.0f - powf(1.0f - a, 1.0f / srf);
        }
        if (!valid) a = 0.0f;                    // reference: a = where(valid, a, 0)
        float one_m = 1.0f - a;

        // ---- 32-wide inclusive product scan of one_m (Hillis-Steele) ----
        float x = one_m;
        #pragma unroll
        for (int off = 1; off < 32; off <<= 1) {
            float y = __shfl_up(x, off);
            if (sub >= off) x *= y;
        }
        float ex = __shfl_up(x, 1);
        if (sub == 0) ex = 1.0f;                 // exclusive transmittance within chunk

        float wgt = (T_prev * ex) * a;
        rgb_r += wgt * cr;
        rgb_g += wgt * cg;
        rgb_b += wgt * cbb;
        acc   += wgt;
        if (valid && (a > 1e-3f)) hk_min = min(hk_min, k);

        // ---- chunk carry ----
        float Tc = __shfl(x, (lane & 32) | 31);  // inclusive product at end of half
        T_prev = T_prev * Tc;

        base += 32;
        // T<1e-7 implies some a>1e-3 (else T >= 0.97^1); truncation err <= 1e-7
        bool active = hit && (base < ns) && (T_prev >= 1e-7f);
        if (__ballot(active) == 0ULL) break;
    }

    // ---- final reductions within each 32-lane half ----
    #pragma unroll
    for (int m = 16; m >= 1; m >>= 1) {
        rgb_r += __shfl_xor(rgb_r, m);
        rgb_g += __shfl_xor(rgb_g, m);
        rgb_b += __shfl_xor(rgb_b, m);
        acc   += __shfl_xor(acc,   m);
        hk_min = min(hk_min, __shfl_xor(hk_min, m));
    }

    if (sub == 0) {
        float depth = 1.0f;
        if (hk_min != 0x7FFFFFFF) {
            float tfh = entry + ((float)hk_min + 0.5f) * step;  // same expr as reference
            depth = (tfh - 0.1f) / 99.9f;
        }
        int oi = (w * RES_H + h) * 5;
        out[oi + 0] = rgb_r;
        out[oi + 1] = rgb_g;
        out[oi + 2] = rgb_b;
        out[oi + 3] = acc;
        out[oi + 4] = depth;
    }
}

extern "C" void kernel_launch(void* const* d_in, const int* in_sizes, int n_in,
                              void* d_out, int out_size, void* d_ws, size_t ws_size,
                              hipStream_t stream) {
    const float* vol = (const float*)d_in[0];
    const float* tf  = (const float*)d_in[1];
    const float* cam = (const float*)d_in[2];
    const int*   sr  = (const int*)d_in[3];
    float* out = (float*)d_out;

    // 65536 rays, 2 rays/wave, 4 waves/block -> 8192 blocks
    raycast_kernel<<<dim3(8192), dim3(256), 0, stream>>>(vol, tf, cam, sr, out);
}